// Round 2
// baseline (472.959 us; speedup 1.0000x reference)
//
#include <hip/hip_runtime.h>
#include <hip/hip_bf16.h>

// RNN_41807211659578 R14: R13 + half-slot swizzle completion + fy prefetch.
// R13 residual conflicts (1.13e7) = fragment b128 reads using only 4 of 8
// 16B bank-slots (half-slot bit constant per instruction) -> 2x DS time.
// Fix: hf ^= (row>>2)&1 swaps 16B halves per row; reads become two b128 at
// base+(h<<4) / base+((h^1)<<4) (h loop-invariant per lane). Writes go
// 4-way -> 2-way (free). Plus: fy(t+1) prefetched at start of P2 via
// 2x-unrolled t-loop (named regs, no dynamic indexing).

typedef unsigned short u16;
typedef unsigned int u32;
typedef unsigned char u8;
typedef __attribute__((ext_vector_type(4))) float f32x4;
typedef __attribute__((ext_vector_type(4))) int i32x4;
typedef __attribute__((ext_vector_type(8))) int i32x8;

#define MFMA128(acc, a, b) \
  (acc) = __builtin_amdgcn_mfma_scale_f32_16x16x128_f8f6f4( \
      (a), (b), (acc), 0, 0, 0, 0x7F7F7F7F, 0, 0x7F7F7F7F)

__device__ __forceinline__ i32x8 ld8(const u8* p) { return *(const i32x8*)p; }
__device__ __forceinline__ void pinV(i32x8& x) { asm volatile("" : "+v"(x)); }

__device__ __forceinline__ u8 f2e4(float v) {
  return (u8)(__builtin_amdgcn_cvt_pk_fp8_f32(v, 0.f, 0, false) & 0xff);
}
__device__ __forceinline__ u32 pk4(float a, float b, float c, float d) {
  u32 p = (u32)__builtin_amdgcn_cvt_pk_fp8_f32(a, b, 0, false);
  return (u32)__builtin_amdgcn_cvt_pk_fp8_f32(c, d, (int)p, true);
}
__device__ __forceinline__ float sigf(float x) {
  return __builtin_amdgcn_rcpf(1.f + __expf(-x));
}
__device__ __forceinline__ float tanh_fast(float x) {
  return 1.f - 2.f * __builtin_amdgcn_rcpf(1.f + __expf(2.f * x));
}

// LDS swizzle: stride 128 B/row.
// phys = row*128 | ((chunk ^ (row&3))<<5) | ((hf ^ ((row>>2)&1))<<4) | (o&15)
// chunk XOR spreads bank-octets across row&3; hf XOR spreads the two 16B
// half-slots across row bit 2 (read instrs hit all 8 slots 8/8-balanced).
__device__ __forceinline__ int swzo(int row, int o) {
  return (row << 7) + ((((o >> 5) ^ row) & 3) << 5) +
         ((((o >> 4) ^ (row >> 2)) & 1) << 4) + (o & 15);
}
// 32B fragment read: two b128 halves, order restored per-lane (h const/lane).
__device__ __forceinline__ i32x8 ldfrag(const u8* b, int row, int kq) {
  const int h = (row >> 2) & 1;
  const int a = (row << 7) + (((kq ^ row) & 3) << 5);
  i32x4 lo = *(const i32x4*)(b + a + (h << 4));
  i32x4 hi = *(const i32x4*)(b + a + ((h ^ 1) << 4));
  return __builtin_shufflevector(lo, hi, 0, 1, 2, 3, 4, 5, 6, 7);
}

// ---- workspace layout (identical to R11/R12/R13) ----
constexpr int E0 = 2 * 384 * 352;
constexpr int E1 = E0 + 2 * 384 * 256;
constexpr int E2 = E1 + 2 * 128 * 128; // Wm1
constexpr int E3 = E2 + 2 * 128 * 128; // Wm2
constexpr int E4 = E3 + 2 * 128 * 128;
constexpr int E5 = E4 + 2 * 128 * 128;
constexpr int NBIAS = 2048;
constexpr int TOTAL = E5 + NBIAS + 4;
constexpr int WB_BYTE_OFF = 16384;

constexpr int WB0A_REL = E5;
constexpr int YBG2_REL = WB0A_REL + 23 * 384 * 128;
constexpr int NA1 = TOTAL;
constexpr int NA2 = NA1 + 23 * 384 * 128;
constexpr int NA3 = NA2 + 48 * 256 * 128;

__global__ void prep_kernel(const float* __restrict__ states,
                            const float* __restrict__ Wih0, const float* __restrict__ Whh0,
                            const float* __restrict__ bih0, const float* __restrict__ bhh0,
                            const float* __restrict__ Wih1, const float* __restrict__ Whh1,
                            const float* __restrict__ bih1, const float* __restrict__ bhh1,
                            const float* __restrict__ W1, const float* __restrict__ W2,
                            u8* __restrict__ wb, float* __restrict__ wsf) {
  for (int idx = blockIdx.x * blockDim.x + threadIdx.x; idx < NA3;
       idx += gridDim.x * blockDim.x) {
    if (idx < E0) {
      int g = idx / 135168;
      int r = idx - g * 135168;
      int j = r / 352;
      int k = r - j * 352;
      const float* wi = Wih0 + (g * 384 + j) * 222;
      float v;
      if (k < 94) v = wi[k];
      else if (k < 96) v = 0.f;
      else if (k < 224) v = wi[k - 2];
      else v = Whh0[(g * 384 + j) * 128 + (k - 224)];
      wb[idx] = f2e4(v);
    } else if (idx < E1) {
      int q = idx - E0;
      int g = q / 98304;
      int r = q - g * 98304;
      int j = r >> 8;
      int k = r & 255;
      float v = (k < 128) ? Wih1[(g * 384 + j) * 128 + k]
                          : Whh1[(g * 384 + j) * 128 + (k - 128)];
      wb[idx] = f2e4(v);
    } else if (idx < E2) {
      int q = idx - E1; int g = q >> 14; int r = q & 16383; int j = r >> 7; int k = r & 127;
      wb[idx] = f2e4(W1[(g * 128 + j) * 128 + k]);
    } else if (idx < E3) {
      int q = idx - E2; int g = q >> 14; int r = q & 16383; int j = r >> 7; int k = r & 127;
      wb[idx] = f2e4(W2[(g * 128 + j) * 128 + k]);
    } else if (idx < E5) {
      wb[idx] = 0;
    } else if (idx < E5 + NBIAS) {
      int q = idx - E5;
      float v;
      if (q < 512)       { int g = q >> 8, j = q & 255;              v = bih0[g*384 + j] + bhh0[g*384 + j]; }
      else if (q < 768)  { int p = q - 512;  int g = p >> 7, j = p & 127; v = bih0[g*384 + 256 + j]; }
      else if (q < 1024) { int p = q - 768;  int g = p >> 7, j = p & 127; v = bhh0[g*384 + 256 + j]; }
      else if (q < 1536) { int p = q - 1024; int g = p >> 8, j = p & 255; v = bih1[g*384 + j] + bhh1[g*384 + j]; }
      else if (q < 1792) { int p = q - 1536; int g = p >> 7, j = p & 127; v = bih1[g*384 + 256 + j]; }
      else               { int p = q - 1792; int g = p >> 7, j = p & 127; v = bhh1[g*384 + 256 + j]; }
      wsf[4 + q] = v;
    } else if (idx < TOTAL) {
      wsf[idx - (E5 + NBIAS)] = 0.f;
    } else if (idx < NA2) {
      int q = idx - NA1;
      int a = q / 49152;
      int r = q - a * 49152;
      int j = r >> 7;
      int k = r & 127;
      const float* wi = Wih0 + (((a >= 12) ? 1 : 0) * 384 + j) * 222;
      float v = (k < 92) ? wi[2 + k] : 0.f;
      if (k == a * 4 + 2) v += wi[0];
      if (k == a * 4 + 3) v += wi[1];
      wb[WB0A_REL + q] = f2e4(v);
    } else {
      int q = idx - NA2;
      int t = q >> 15;
      int r = q & 32767;
      int row = r >> 7;
      int k = r & 127;
      float v = (k < 92) ? states[((size_t)t * 256 + row) * 92 + k] : 0.f;
      wb[YBG2_REL + q] = f2e4(v);
    }
  }
}

__global__ __launch_bounds__(512, 2) __attribute__((amdgpu_waves_per_eu(2, 2)))
void rnn_kernel(const float* __restrict__ states,
                const u8* __restrict__ wb,
                float* __restrict__ wsf,
                const float* __restrict__ b1g,
                const float* __restrict__ b2g,
                const float* __restrict__ Wmg,
                const float* __restrict__ bmg) {
  const int blk = blockIdx.x;
  const int g = (blk < 96) ? 0 : 1;
  const int r0 = (g == 0) ? (blk * 32) : ((blk - 96) * 32);
  const int aAg = (g == 0 ? 0 : 12) + (r0 >> 8);
  const int b0 = r0 & 255;

  const int tid = threadIdx.x;
  const int wid = tid >> 6;
  const int ln = tid & 63;
  const int j_in = ln & 15;
  const int kq = ln >> 4;
  const int c0 = wid * 16 + kq * 4;
  const int jh = wid * 16 + j_in;

  __shared__ __align__(64) u8 h0b[2][32 * 128];
  __shared__ __align__(64) u8 h1b[2][32 * 128];
  __shared__ __align__(64) u8 d1b[32 * 128];
  __shared__ __align__(64) u8 d2b[32 * 128];
  __shared__ __align__(16) float bias[1536];
  __shared__ float dmv[48][32][2];
  __shared__ float red[8][3];

  const u8* W0   = wb + g * 135168;
  const u8* W1c  = wb + E0 + g * 98304;
  const u8* Wm1p = wb + E1 + g * 16384;
  const u8* Wm2p = wb + E2 + g * 16384;
  const u8* WB0A = wb + WB0A_REL + aAg * 49152;
  const u8* YBG  = wb + YBG2_REL;

  // ---- weights: 17 i32x8 (136 regs), "+v" opaque pins ----
  i32x8 w0r0 = ld8(WB0A + jh * 128 + kq * 32);
  i32x8 w0r1 = ld8(W0 + jh * 352 + 96 + kq * 32);
  i32x8 w0r2 = ld8(W0 + jh * 352 + 224 + kq * 32);
  i32x8 w0z0 = ld8(WB0A + (128 + jh) * 128 + kq * 32);
  i32x8 w0z1 = ld8(W0 + (128 + jh) * 352 + 96 + kq * 32);
  i32x8 w0z2 = ld8(W0 + (128 + jh) * 352 + 224 + kq * 32);
  i32x8 w0n0 = ld8(WB0A + (256 + jh) * 128 + kq * 32);
  i32x8 w0n1 = ld8(W0 + (256 + jh) * 352 + 96 + kq * 32);
  i32x8 wn0  = ld8(W0 + (256 + jh) * 352 + 224 + kq * 32);
  i32x8 w1r0 = ld8(W1c + jh * 256 + kq * 32);
  i32x8 w1r1 = ld8(W1c + jh * 256 + 128 + kq * 32);
  i32x8 w1z0 = ld8(W1c + (128 + jh) * 256 + kq * 32);
  i32x8 w1z1 = ld8(W1c + (128 + jh) * 256 + 128 + kq * 32);
  i32x8 w1n0 = ld8(W1c + (256 + jh) * 256 + kq * 32);
  i32x8 wn1  = ld8(W1c + (256 + jh) * 256 + 128 + kq * 32);
  i32x8 wm1  = ld8(Wm1p + jh * 128 + kq * 32);
  i32x8 wm2  = ld8(Wm2p + jh * 128 + kq * 32);
  pinV(w0r0); pinV(w0r1); pinV(w0r2);
  pinV(w0z0); pinV(w0z1); pinV(w0z2);
  pinV(w0n0); pinV(w0n1); pinV(wn0);
  pinV(w1r0); pinV(w1r1); pinV(w1z0); pinV(w1z1);
  pinV(w1n0); pinV(wn1); pinV(wm1); pinV(wm2);

  // ---- biases + Wm into LDS ----
  for (int i = tid; i < 1536; i += 512) {
    float v;
    if (i < 256)       v = wsf[4 + g * 256 + i];
    else if (i < 384)  v = wsf[516 + g * 128 + (i - 256)];
    else if (i < 512)  v = wsf[772 + g * 128 + (i - 384)];
    else if (i < 768)  v = wsf[1028 + g * 256 + (i - 512)];
    else if (i < 896)  v = wsf[1540 + g * 128 + (i - 768)];
    else if (i < 1024) v = wsf[1796 + g * 128 + (i - 896)];
    else if (i < 1152) v = b1g[g * 128 + (i - 1024)];
    else if (i < 1280) v = b2g[g * 128 + (i - 1152)];
    else               v = Wmg[g * 256 + (i - 1280)];
    bias[i] = v;
  }
  for (int i = tid; i < 32 * 128; i += 512) { h0b[0][i] = 0; h1b[0][i] = 0; }

  f32x4 hv0[2] = {{0,0,0,0},{0,0,0,0}};
  f32x4 hv1[2] = {{0,0,0,0},{0,0,0,0}};
  __syncthreads();

  // fy fragments for t=0 preloaded; prefetch t+1 during P2 each step.
  i32x8 fyA0 = ld8(YBG + (b0 + j_in) * 128 + kq * 32);
  i32x8 fyA1 = ld8(YBG + (b0 + 16 + j_in) * 128 + kq * 32);
  i32x8 fyB0, fyB1;

#define STEP(T, FC0, FC1, FN0, FN1)                                          \
  {                                                                          \
    const int cur = (T) & 1, nxt = cur ^ 1;                                  \
    const u8* h0c = h0b[cur]; u8* h0n = h0b[nxt];                            \
    const u8* h1c = h1b[cur]; u8* h1n = h1b[nxt];                            \
    i32x8 fh1k[2];                                                           \
    { /* ==== P1: MLP1 + GRU0 (+h0n write) ==== */                           \
      f32x4 b1v = *(const f32x4*)(bias + 1024 + c0);                         \
      f32x4 brv = *(const f32x4*)(bias + c0);                                \
      f32x4 bzv = *(const f32x4*)(bias + 128 + c0);                          \
      f32x4 biv = *(const f32x4*)(bias + 256 + c0);                          \
      f32x4 bhv = *(const f32x4*)(bias + 384 + c0);                          \
      _Pragma("unroll")                                                      \
      for (int nt = 0; nt < 2; ++nt) {                                       \
        const int row = nt * 16 + j_in;                                      \
        i32x8 fy  = nt ? (FC1) : (FC0);                                      \
        i32x8 fh1 = ldfrag(h1c, row, kq);                                    \
        i32x8 fh0 = ldfrag(h0c, row, kq);                                    \
        fh1k[nt] = fh1;                                                      \
        f32x4 mm = {0, 0, 0, 0};                                             \
        MFMA128(mm, wm1, fh1);                                               \
        f32x4 aR = {0,0,0,0}, aZ = {0,0,0,0}, aN = {0,0,0,0}, aG = {0,0,0,0};\
        MFMA128(aR, w0r0, fy);  MFMA128(aZ, w0z0, fy);  MFMA128(aN, w0n0, fy);\
        MFMA128(aR, w0r1, fh1); MFMA128(aZ, w0z1, fh1); MFMA128(aN, w0n1, fh1);\
        MFMA128(aR, w0r2, fh0); MFMA128(aZ, w0z2, fh0); MFMA128(aG, wn0, fh0);\
        *(u32*)(d1b + swzo(row, c0)) =                                       \
          pk4(fmaxf(mm[0]+b1v[0],0.f), fmaxf(mm[1]+b1v[1],0.f),              \
              fmaxf(mm[2]+b1v[2],0.f), fmaxf(mm[3]+b1v[3],0.f));             \
        _Pragma("unroll")                                                    \
        for (int i = 0; i < 4; ++i) {                                        \
          float rv = sigf(aR[i] + brv[i]);                                   \
          float zv = sigf(aZ[i] + bzv[i]);                                   \
          float nv = tanh_fast(aN[i] + biv[i] + rv * (aG[i] + bhv[i]));      \
          hv0[nt][i] = (1.f - zv) * nv + zv * hv0[nt][i];                    \
        }                                                                    \
        *(u32*)(h0n + swzo(row, c0)) =                                       \
          pk4(hv0[nt][0], hv0[nt][1], hv0[nt][2], hv0[nt][3]);               \
      }                                                                      \
    }                                                                        \
    /* dm(t-1): reads d2b written in P2 of t-1 (separated by B2) */          \
    if ((T) > 0) {                                                           \
      int row = tid >> 4, c = (tid >> 3) & 1, part = tid & 7;                \
      const float* wmr = bias + 1280 + c * 128 + part * 16;                  \
      float s = 0.f;                                                         \
      _Pragma("unroll")                                                      \
      for (int q = 0; q < 4; ++q) {                                          \
        u32 w = *(const u32*)(d2b + swzo(row, part * 16 + q * 4));           \
        s += wmr[q * 4 + 0] * __builtin_amdgcn_cvt_f32_fp8((int)w, 0);       \
        s += wmr[q * 4 + 1] * __builtin_amdgcn_cvt_f32_fp8((int)w, 1);       \
        s += wmr[q * 4 + 2] * __builtin_amdgcn_cvt_f32_fp8((int)w, 2);       \
        s += wmr[q * 4 + 3] * __builtin_amdgcn_cvt_f32_fp8((int)w, 3);       \
      }                                                                      \
      s += __shfl_xor(s, 1); s += __shfl_xor(s, 2); s += __shfl_xor(s, 4);   \
      if (part == 0) dmv[(T) - 1][row][c] = s;                               \
    }                                                                        \
    __syncthreads(); /* B1 */                                                \
    { /* ==== P2: MLP2 + GRU1 (+h1n write) + fy(t+1) prefetch ==== */        \
      if ((T) < 47) {                                                        \
        const u8* ytn = YBG + ((T) + 1) * 32768;                             \
        FN0 = ld8(ytn + (b0 + j_in) * 128 + kq * 32);                        \
        FN1 = ld8(ytn + (b0 + 16 + j_in) * 128 + kq * 32);                   \
      }                                                                      \
      f32x4 b2v = *(const f32x4*)(bias + 1152 + c0);                         \
      f32x4 brv = *(const f32x4*)(bias + 512 + c0);                          \
      f32x4 bzv = *(const f32x4*)(bias + 640 + c0);                          \
      f32x4 biv = *(const f32x4*)(bias + 768 + c0);                          \
      f32x4 bhv = *(const f32x4*)(bias + 896 + c0);                          \
      _Pragma("unroll")                                                      \
      for (int nt = 0; nt < 2; ++nt) {                                       \
        const int row = nt * 16 + j_in;                                      \
        i32x8 fd1 = ldfrag(d1b, row, kq);                                    \
        i32x8 fg0 = ldfrag(h0n, row, kq);                                    \
        f32x4 mm = {0, 0, 0, 0};                                             \
        MFMA128(mm, wm2, fd1);                                               \
        f32x4 aR = {0,0,0,0}, aZ = {0,0,0,0}, aN = {0,0,0,0}, aG = {0,0,0,0};\
        MFMA128(aR, w1r0, fg0);      MFMA128(aZ, w1z0, fg0);                 \
        MFMA128(aN, w1n0, fg0);                                              \
        MFMA128(aR, w1r1, fh1k[nt]); MFMA128(aZ, w1z1, fh1k[nt]);            \
        MFMA128(aG, wn1, fh1k[nt]);                                          \
        *(u32*)(d2b + swzo(row, c0)) =                                       \
          pk4(fmaxf(mm[0]+b2v[0],0.f), fmaxf(mm[1]+b2v[1],0.f),              \
              fmaxf(mm[2]+b2v[2],0.f), fmaxf(mm[3]+b2v[3],0.f));             \
        _Pragma("unroll")                                                    \
        for (int i = 0; i < 4; ++i) {                                        \
          float rv = sigf(aR[i] + brv[i]);                                   \
          float zv = sigf(aZ[i] + bzv[i]);                                   \
          float nv = tanh_fast(aN[i] + biv[i] + rv * (aG[i] + bhv[i]));      \
          hv1[nt][i] = (1.f - zv) * nv + zv * hv1[nt][i];                    \
        }                                                                    \
        *(u32*)(h1n + swzo(row, c0)) =                                       \
          pk4(hv1[nt][0], hv1[nt][1], hv1[nt][2], hv1[nt][3]);               \
      }                                                                      \
    }                                                                        \
    __syncthreads(); /* B2 */                                                \
  }

  for (int tq = 0; tq < 24; ++tq) {
    STEP(tq * 2,     fyA0, fyA1, fyB0, fyB1);
    STEP(tq * 2 + 1, fyB0, fyB1, fyA0, fyA1);
  }
#undef STEP

  // ==== tail: dm(47) ====
  {
    int row = tid >> 4, c = (tid >> 3) & 1, part = tid & 7;
    const float* wmr = bias + 1280 + c * 128 + part * 16;
    float s = 0.f;
#pragma unroll
    for (int q = 0; q < 4; ++q) {
      u32 w = *(const u32*)(d2b + swzo(row, part * 16 + q * 4));
      s += wmr[q * 4 + 0] * __builtin_amdgcn_cvt_f32_fp8((int)w, 0);
      s += wmr[q * 4 + 1] * __builtin_amdgcn_cvt_f32_fp8((int)w, 1);
      s += wmr[q * 4 + 2] * __builtin_amdgcn_cvt_f32_fp8((int)w, 2);
      s += wmr[q * 4 + 3] * __builtin_amdgcn_cvt_f32_fp8((int)w, 3);
    }
    s += __shfl_xor(s, 1); s += __shfl_xor(s, 2); s += __shfl_xor(s, 4);
    if (part == 0) dmv[47][row][c] = s;
  }
  __syncthreads();

  // ---- error phase (post-loop, fully parallel) ----
  float accL = 0.f, accEp = 0.f, accEv = 0.f;
  const float bm0 = bmg[g * 2], bm1 = bmg[g * 2 + 1];
  for (int idx = tid; idx < 1536; idx += 512) {
    int t = idx >> 5, row = idx & 31;
    const float* sr = states + ((size_t)(t * 256 + b0 + row)) * 92 + aAg * 4;
    const float* sn = sr + 256 * 92;
    float dx = dmv[t][row][0] + bm0 - sn[2];
    float dy = dmv[t][row][1] + bm1 - sn[3];
    float e = sqrtf(dx * dx + dy * dy);
    accL += e;
    if (t >= 12) {
      accEv += e;
      float ex = sr[0] + 0.1f * sr[2] - sn[0];
      float ey = sr[1] + 0.1f * sr[3] - sn[1];
      accEp += sqrtf(ex * ex + ey * ey);
    }
  }
#pragma unroll
  for (int k = 1; k < 64; k <<= 1) {
    accL  += __shfl_xor(accL, k);
    accEp += __shfl_xor(accEp, k);
    accEv += __shfl_xor(accEv, k);
  }
  if (ln == 0) { red[wid][0] = accL; red[wid][1] = accEp; red[wid][2] = accEv; }
  __syncthreads();
  if (tid < 3) {
    float s = 0.f;
    for (int i = 0; i < 8; ++i) s += red[i][tid];
    atomicAdd(&wsf[tid], s);
  }
}

__global__ void fin_kernel(const float* __restrict__ wacc, float* __restrict__ out) {
  if (threadIdx.x == 0 && blockIdx.x == 0) {
    out[0] = wacc[0] / 1104.f;
    out[1] = wacc[1] / 828.f;
    out[2] = wacc[2] / 828.f;
  }
}

extern "C" void kernel_launch(void* const* d_in, const int* in_sizes, int n_in,
                              void* d_out, int out_size, void* d_ws, size_t ws_size,
                              hipStream_t stream) {
  const float* states = (const float*)d_in[0];
  const float* Wih0 = (const float*)d_in[1];
  const float* Whh0 = (const float*)d_in[2];
  const float* bih0 = (const float*)d_in[3];
  const float* bhh0 = (const float*)d_in[4];
  const float* Wih1 = (const float*)d_in[5];
  const float* Whh1 = (const float*)d_in[6];
  const float* bih1 = (const float*)d_in[7];
  const float* bhh1 = (const float*)d_in[8];
  const float* W1   = (const float*)d_in[9];
  const float* b1   = (const float*)d_in[10];
  const float* W2   = (const float*)d_in[11];
  const float* b2   = (const float*)d_in[12];
  const float* Wm   = (const float*)d_in[13];
  const float* bm   = (const float*)d_in[14];

  float* wsf = (float*)d_ws;
  u8* wb = (u8*)d_ws + WB_BYTE_OFF;

  int prep_blocks = (NA3 + 255) / 256;
  if (prep_blocks > 2048) prep_blocks = 2048;
  prep_kernel<<<prep_blocks, 256, 0, stream>>>(states, Wih0, Whh0, bih0, bhh0,
                                               Wih1, Whh1, bih1, bhh1,
                                               W1, W2, wb, wsf);
  rnn_kernel<<<184, 512, 0, stream>>>(states, wb, wsf, b1, b2, Wm, bm);
  fin_kernel<<<1, 64, 0, stream>>>(wsf, (float*)d_out);
}

// Round 3
// 274.898 us; speedup vs baseline: 1.7205x; 1.7205x over previous
//
#include <hip/hip_runtime.h>
#include <hip/hip_bf16.h>

// RNN_41807211659578 R15: R13 structure + R14's half-slot swizzle; fy
// prefetch REVERTED (it cost 32 VGPRs over the 128 cap at 2 blocks/CU ->
// scratch spills, FETCH 9.6->315 MB, 2x regression). Swizzle kept:
// phys = row*128 | ((chunk^row)&3)<<5 | ((hf^(row>>2))&1)<<4 | o&15
// -> fragment b128 reads hit all 8 16B bank-slots 8/8-balanced
// (conflicts 1.13e7 -> 4.5e6 measured in R14).

typedef unsigned short u16;
typedef unsigned int u32;
typedef unsigned char u8;
typedef __attribute__((ext_vector_type(4))) float f32x4;
typedef __attribute__((ext_vector_type(4))) int i32x4;
typedef __attribute__((ext_vector_type(8))) int i32x8;

#define MFMA128(acc, a, b) \
  (acc) = __builtin_amdgcn_mfma_scale_f32_16x16x128_f8f6f4( \
      (a), (b), (acc), 0, 0, 0, 0x7F7F7F7F, 0, 0x7F7F7F7F)

__device__ __forceinline__ i32x8 ld8(const u8* p) { return *(const i32x8*)p; }
__device__ __forceinline__ void pinV(i32x8& x) { asm volatile("" : "+v"(x)); }

__device__ __forceinline__ u8 f2e4(float v) {
  return (u8)(__builtin_amdgcn_cvt_pk_fp8_f32(v, 0.f, 0, false) & 0xff);
}
__device__ __forceinline__ u32 pk4(float a, float b, float c, float d) {
  u32 p = (u32)__builtin_amdgcn_cvt_pk_fp8_f32(a, b, 0, false);
  return (u32)__builtin_amdgcn_cvt_pk_fp8_f32(c, d, (int)p, true);
}
__device__ __forceinline__ float sigf(float x) {
  return __builtin_amdgcn_rcpf(1.f + __expf(-x));
}
__device__ __forceinline__ float tanh_fast(float x) {
  return 1.f - 2.f * __builtin_amdgcn_rcpf(1.f + __expf(2.f * x));
}

// LDS swizzle: stride 128 B/row.
__device__ __forceinline__ int swzo(int row, int o) {
  return (row << 7) + ((((o >> 5) ^ row) & 3) << 5) +
         ((((o >> 4) ^ (row >> 2)) & 1) << 4) + (o & 15);
}
// 32B fragment read: two b128 halves, logical order restored per-lane.
__device__ __forceinline__ i32x8 ldfrag(const u8* b, int row, int kq) {
  const int h = (row >> 2) & 1;
  const int a = (row << 7) + (((kq ^ row) & 3) << 5);
  i32x4 lo = *(const i32x4*)(b + a + (h << 4));
  i32x4 hi = *(const i32x4*)(b + a + ((h ^ 1) << 4));
  return __builtin_shufflevector(lo, hi, 0, 1, 2, 3, 4, 5, 6, 7);
}

// ---- workspace layout (identical to R11..R14) ----
constexpr int E0 = 2 * 384 * 352;
constexpr int E1 = E0 + 2 * 384 * 256;
constexpr int E2 = E1 + 2 * 128 * 128; // Wm1
constexpr int E3 = E2 + 2 * 128 * 128; // Wm2
constexpr int E4 = E3 + 2 * 128 * 128;
constexpr int E5 = E4 + 2 * 128 * 128;
constexpr int NBIAS = 2048;
constexpr int TOTAL = E5 + NBIAS + 4;
constexpr int WB_BYTE_OFF = 16384;

constexpr int WB0A_REL = E5;
constexpr int YBG2_REL = WB0A_REL + 23 * 384 * 128;
constexpr int NA1 = TOTAL;
constexpr int NA2 = NA1 + 23 * 384 * 128;
constexpr int NA3 = NA2 + 48 * 256 * 128;

__global__ void prep_kernel(const float* __restrict__ states,
                            const float* __restrict__ Wih0, const float* __restrict__ Whh0,
                            const float* __restrict__ bih0, const float* __restrict__ bhh0,
                            const float* __restrict__ Wih1, const float* __restrict__ Whh1,
                            const float* __restrict__ bih1, const float* __restrict__ bhh1,
                            const float* __restrict__ W1, const float* __restrict__ W2,
                            u8* __restrict__ wb, float* __restrict__ wsf) {
  for (int idx = blockIdx.x * blockDim.x + threadIdx.x; idx < NA3;
       idx += gridDim.x * blockDim.x) {
    if (idx < E0) {
      int g = idx / 135168;
      int r = idx - g * 135168;
      int j = r / 352;
      int k = r - j * 352;
      const float* wi = Wih0 + (g * 384 + j) * 222;
      float v;
      if (k < 94) v = wi[k];
      else if (k < 96) v = 0.f;
      else if (k < 224) v = wi[k - 2];
      else v = Whh0[(g * 384 + j) * 128 + (k - 224)];
      wb[idx] = f2e4(v);
    } else if (idx < E1) {
      int q = idx - E0;
      int g = q / 98304;
      int r = q - g * 98304;
      int j = r >> 8;
      int k = r & 255;
      float v = (k < 128) ? Wih1[(g * 384 + j) * 128 + k]
                          : Whh1[(g * 384 + j) * 128 + (k - 128)];
      wb[idx] = f2e4(v);
    } else if (idx < E2) {
      int q = idx - E1; int g = q >> 14; int r = q & 16383; int j = r >> 7; int k = r & 127;
      wb[idx] = f2e4(W1[(g * 128 + j) * 128 + k]);
    } else if (idx < E3) {
      int q = idx - E2; int g = q >> 14; int r = q & 16383; int j = r >> 7; int k = r & 127;
      wb[idx] = f2e4(W2[(g * 128 + j) * 128 + k]);
    } else if (idx < E5) {
      wb[idx] = 0;
    } else if (idx < E5 + NBIAS) {
      int q = idx - E5;
      float v;
      if (q < 512)       { int g = q >> 8, j = q & 255;              v = bih0[g*384 + j] + bhh0[g*384 + j]; }
      else if (q < 768)  { int p = q - 512;  int g = p >> 7, j = p & 127; v = bih0[g*384 + 256 + j]; }
      else if (q < 1024) { int p = q - 768;  int g = p >> 7, j = p & 127; v = bhh0[g*384 + 256 + j]; }
      else if (q < 1536) { int p = q - 1024; int g = p >> 8, j = p & 255; v = bih1[g*384 + j] + bhh1[g*384 + j]; }
      else if (q < 1792) { int p = q - 1536; int g = p >> 7, j = p & 127; v = bih1[g*384 + 256 + j]; }
      else               { int p = q - 1792; int g = p >> 7, j = p & 127; v = bhh1[g*384 + 256 + j]; }
      wsf[4 + q] = v;
    } else if (idx < TOTAL) {
      wsf[idx - (E5 + NBIAS)] = 0.f;
    } else if (idx < NA2) {
      int q = idx - NA1;
      int a = q / 49152;
      int r = q - a * 49152;
      int j = r >> 7;
      int k = r & 127;
      const float* wi = Wih0 + (((a >= 12) ? 1 : 0) * 384 + j) * 222;
      float v = (k < 92) ? wi[2 + k] : 0.f;
      if (k == a * 4 + 2) v += wi[0];
      if (k == a * 4 + 3) v += wi[1];
      wb[WB0A_REL + q] = f2e4(v);
    } else {
      int q = idx - NA2;
      int t = q >> 15;
      int r = q & 32767;
      int row = r >> 7;
      int k = r & 127;
      float v = (k < 92) ? states[((size_t)t * 256 + row) * 92 + k] : 0.f;
      wb[YBG2_REL + q] = f2e4(v);
    }
  }
}

__global__ __launch_bounds__(512, 2) __attribute__((amdgpu_waves_per_eu(2, 2)))
void rnn_kernel(const float* __restrict__ states,
                const u8* __restrict__ wb,
                float* __restrict__ wsf,
                const float* __restrict__ b1g,
                const float* __restrict__ b2g,
                const float* __restrict__ Wmg,
                const float* __restrict__ bmg) {
  const int blk = blockIdx.x;
  const int g = (blk < 96) ? 0 : 1;
  const int r0 = (g == 0) ? (blk * 32) : ((blk - 96) * 32);
  const int aAg = (g == 0 ? 0 : 12) + (r0 >> 8);
  const int b0 = r0 & 255;

  const int tid = threadIdx.x;
  const int wid = tid >> 6;
  const int ln = tid & 63;
  const int j_in = ln & 15;
  const int kq = ln >> 4;
  const int c0 = wid * 16 + kq * 4;
  const int jh = wid * 16 + j_in;

  __shared__ __align__(64) u8 h0b[2][32 * 128];
  __shared__ __align__(64) u8 h1b[2][32 * 128];
  __shared__ __align__(64) u8 d1b[32 * 128];
  __shared__ __align__(64) u8 d2b[32 * 128];
  __shared__ __align__(16) float bias[1536];
  __shared__ float dmv[48][32][2];
  __shared__ float red[8][3];

  const u8* W0   = wb + g * 135168;
  const u8* W1c  = wb + E0 + g * 98304;
  const u8* Wm1p = wb + E1 + g * 16384;
  const u8* Wm2p = wb + E2 + g * 16384;
  const u8* WB0A = wb + WB0A_REL + aAg * 49152;
  const u8* YBG  = wb + YBG2_REL;

  // ---- weights: 17 i32x8 (136 regs), "+v" opaque pins ----
  i32x8 w0r0 = ld8(WB0A + jh * 128 + kq * 32);
  i32x8 w0r1 = ld8(W0 + jh * 352 + 96 + kq * 32);
  i32x8 w0r2 = ld8(W0 + jh * 352 + 224 + kq * 32);
  i32x8 w0z0 = ld8(WB0A + (128 + jh) * 128 + kq * 32);
  i32x8 w0z1 = ld8(W0 + (128 + jh) * 352 + 96 + kq * 32);
  i32x8 w0z2 = ld8(W0 + (128 + jh) * 352 + 224 + kq * 32);
  i32x8 w0n0 = ld8(WB0A + (256 + jh) * 128 + kq * 32);
  i32x8 w0n1 = ld8(W0 + (256 + jh) * 352 + 96 + kq * 32);
  i32x8 wn0  = ld8(W0 + (256 + jh) * 352 + 224 + kq * 32);
  i32x8 w1r0 = ld8(W1c + jh * 256 + kq * 32);
  i32x8 w1r1 = ld8(W1c + jh * 256 + 128 + kq * 32);
  i32x8 w1z0 = ld8(W1c + (128 + jh) * 256 + kq * 32);
  i32x8 w1z1 = ld8(W1c + (128 + jh) * 256 + 128 + kq * 32);
  i32x8 w1n0 = ld8(W1c + (256 + jh) * 256 + kq * 32);
  i32x8 wn1  = ld8(W1c + (256 + jh) * 256 + 128 + kq * 32);
  i32x8 wm1  = ld8(Wm1p + jh * 128 + kq * 32);
  i32x8 wm2  = ld8(Wm2p + jh * 128 + kq * 32);
  pinV(w0r0); pinV(w0r1); pinV(w0r2);
  pinV(w0z0); pinV(w0z1); pinV(w0z2);
  pinV(w0n0); pinV(w0n1); pinV(wn0);
  pinV(w1r0); pinV(w1r1); pinV(w1z0); pinV(w1z1);
  pinV(w1n0); pinV(wn1); pinV(wm1); pinV(wm2);

  // ---- biases + Wm into LDS ----
  for (int i = tid; i < 1536; i += 512) {
    float v;
    if (i < 256)       v = wsf[4 + g * 256 + i];
    else if (i < 384)  v = wsf[516 + g * 128 + (i - 256)];
    else if (i < 512)  v = wsf[772 + g * 128 + (i - 384)];
    else if (i < 768)  v = wsf[1028 + g * 256 + (i - 512)];
    else if (i < 896)  v = wsf[1540 + g * 128 + (i - 768)];
    else if (i < 1024) v = wsf[1796 + g * 128 + (i - 896)];
    else if (i < 1152) v = b1g[g * 128 + (i - 1024)];
    else if (i < 1280) v = b2g[g * 128 + (i - 1152)];
    else               v = Wmg[g * 256 + (i - 1280)];
    bias[i] = v;
  }
  for (int i = tid; i < 32 * 128; i += 512) { h0b[0][i] = 0; h1b[0][i] = 0; }

  f32x4 hv0[2] = {{0,0,0,0},{0,0,0,0}};
  f32x4 hv1[2] = {{0,0,0,0},{0,0,0,0}};
  __syncthreads();

  for (int t = 0; t < 48; ++t) {
    const int cur = t & 1, nxt = cur ^ 1;
    const u8* h0c = h0b[cur]; u8* h0n = h0b[nxt];
    const u8* h1c = h1b[cur]; u8* h1n = h1b[nxt];
    const u8* yt = YBG + t * 32768;

    // ==== P1: MLP1 + GRU0 (+h0n write) + dm(t-1) ====
    i32x8 fh1k[2]; // carried to P2 for GRU1
    {
      f32x4 b1v = *(const f32x4*)(bias + 1024 + c0);
      f32x4 brv = *(const f32x4*)(bias + c0);
      f32x4 bzv = *(const f32x4*)(bias + 128 + c0);
      f32x4 biv = *(const f32x4*)(bias + 256 + c0);
      f32x4 bhv = *(const f32x4*)(bias + 384 + c0);
#pragma unroll
      for (int nt = 0; nt < 2; ++nt) {
        const int row = nt * 16 + j_in;
        i32x8 fy  = ld8(yt + (b0 + row) * 128 + kq * 32);
        i32x8 fh1 = ldfrag(h1c, row, kq);
        i32x8 fh0 = ldfrag(h0c, row, kq);
        fh1k[nt] = fh1;
        f32x4 mm = {0,0,0,0};
        MFMA128(mm, wm1, fh1);
        f32x4 aR = {0,0,0,0}, aZ = {0,0,0,0}, aN = {0,0,0,0}, aG = {0,0,0,0};
        MFMA128(aR, w0r0, fy);  MFMA128(aZ, w0z0, fy);  MFMA128(aN, w0n0, fy);
        MFMA128(aR, w0r1, fh1); MFMA128(aZ, w0z1, fh1); MFMA128(aN, w0n1, fh1);
        MFMA128(aR, w0r2, fh0); MFMA128(aZ, w0z2, fh0); MFMA128(aG, wn0, fh0);
        *(u32*)(d1b + swzo(row, c0)) =
          pk4(fmaxf(mm[0]+b1v[0],0.f), fmaxf(mm[1]+b1v[1],0.f),
              fmaxf(mm[2]+b1v[2],0.f), fmaxf(mm[3]+b1v[3],0.f));
#pragma unroll
        for (int i = 0; i < 4; ++i) {
          float rv = sigf(aR[i] + brv[i]);
          float zv = sigf(aZ[i] + bzv[i]);
          float nv = tanh_fast(aN[i] + biv[i] + rv * (aG[i] + bhv[i]));
          hv0[nt][i] = (1.f - zv) * nv + zv * hv0[nt][i];
        }
        *(u32*)(h0n + swzo(row, c0)) = pk4(hv0[nt][0], hv0[nt][1], hv0[nt][2], hv0[nt][3]);
      }
    }
    // dm(t-1): reads d2b written in P2 of t-1 (separated by B2)
    if (t > 0) {
      int row = tid >> 4, c = (tid >> 3) & 1, part = tid & 7;
      const float* wmr = bias + 1280 + c * 128 + part * 16;
      float s = 0.f;
#pragma unroll
      for (int q = 0; q < 4; ++q) {
        u32 w = *(const u32*)(d2b + swzo(row, part * 16 + q * 4));
        s += wmr[q * 4 + 0] * __builtin_amdgcn_cvt_f32_fp8((int)w, 0);
        s += wmr[q * 4 + 1] * __builtin_amdgcn_cvt_f32_fp8((int)w, 1);
        s += wmr[q * 4 + 2] * __builtin_amdgcn_cvt_f32_fp8((int)w, 2);
        s += wmr[q * 4 + 3] * __builtin_amdgcn_cvt_f32_fp8((int)w, 3);
      }
      s += __shfl_xor(s, 1); s += __shfl_xor(s, 2); s += __shfl_xor(s, 4);
      if (part == 0) dmv[t - 1][row][c] = s;
    }
    __syncthreads(); // B1: d1b + h0n ready; all reads of h0c/h1c/d2b done

    // ==== P2: MLP2 + GRU1 (+h1n write) ====
    {
      f32x4 b2v = *(const f32x4*)(bias + 1152 + c0);
      f32x4 brv = *(const f32x4*)(bias + 512 + c0);
      f32x4 bzv = *(const f32x4*)(bias + 640 + c0);
      f32x4 biv = *(const f32x4*)(bias + 768 + c0);
      f32x4 bhv = *(const f32x4*)(bias + 896 + c0);
#pragma unroll
      for (int nt = 0; nt < 2; ++nt) {
        const int row = nt * 16 + j_in;
        i32x8 fd1 = ldfrag(d1b, row, kq);
        i32x8 fg0 = ldfrag(h0n, row, kq);
        f32x4 mm = {0,0,0,0};
        MFMA128(mm, wm2, fd1);
        f32x4 aR = {0,0,0,0}, aZ = {0,0,0,0}, aN = {0,0,0,0}, aG = {0,0,0,0};
        MFMA128(aR, w1r0, fg0);      MFMA128(aZ, w1z0, fg0);      MFMA128(aN, w1n0, fg0);
        MFMA128(aR, w1r1, fh1k[nt]); MFMA128(aZ, w1z1, fh1k[nt]); MFMA128(aG, wn1, fh1k[nt]);
        *(u32*)(d2b + swzo(row, c0)) =
          pk4(fmaxf(mm[0]+b2v[0],0.f), fmaxf(mm[1]+b2v[1],0.f),
              fmaxf(mm[2]+b2v[2],0.f), fmaxf(mm[3]+b2v[3],0.f));
#pragma unroll
        for (int i = 0; i < 4; ++i) {
          float rv = sigf(aR[i] + brv[i]);
          float zv = sigf(aZ[i] + bzv[i]);
          float nv = tanh_fast(aN[i] + biv[i] + rv * (aG[i] + bhv[i]));
          hv1[nt][i] = (1.f - zv) * nv + zv * hv1[nt][i];
        }
        *(u32*)(h1n + swzo(row, c0)) = pk4(hv1[nt][0], hv1[nt][1], hv1[nt][2], hv1[nt][3]);
      }
    }
    __syncthreads(); // B2: d2b + h1n ready
  }

  // ==== tail: dm(47) ====
  {
    int row = tid >> 4, c = (tid >> 3) & 1, part = tid & 7;
    const float* wmr = bias + 1280 + c * 128 + part * 16;
    float s = 0.f;
#pragma unroll
    for (int q = 0; q < 4; ++q) {
      u32 w = *(const u32*)(d2b + swzo(row, part * 16 + q * 4));
      s += wmr[q * 4 + 0] * __builtin_amdgcn_cvt_f32_fp8((int)w, 0);
      s += wmr[q * 4 + 1] * __builtin_amdgcn_cvt_f32_fp8((int)w, 1);
      s += wmr[q * 4 + 2] * __builtin_amdgcn_cvt_f32_fp8((int)w, 2);
      s += wmr[q * 4 + 3] * __builtin_amdgcn_cvt_f32_fp8((int)w, 3);
    }
    s += __shfl_xor(s, 1); s += __shfl_xor(s, 2); s += __shfl_xor(s, 4);
    if (part == 0) dmv[47][row][c] = s;
  }
  __syncthreads();

  // ---- error phase (post-loop, fully parallel) ----
  float accL = 0.f, accEp = 0.f, accEv = 0.f;
  const float bm0 = bmg[g * 2], bm1 = bmg[g * 2 + 1];
  for (int idx = tid; idx < 1536; idx += 512) {
    int t = idx >> 5, row = idx & 31;
    const float* sr = states + ((size_t)(t * 256 + b0 + row)) * 92 + aAg * 4;
    const float* sn = sr + 256 * 92;
    float dx = dmv[t][row][0] + bm0 - sn[2];
    float dy = dmv[t][row][1] + bm1 - sn[3];
    float e = sqrtf(dx * dx + dy * dy);
    accL += e;
    if (t >= 12) {
      accEv += e;
      float ex = sr[0] + 0.1f * sr[2] - sn[0];
      float ey = sr[1] + 0.1f * sr[3] - sn[1];
      accEp += sqrtf(ex * ex + ey * ey);
    }
  }
#pragma unroll
  for (int k = 1; k < 64; k <<= 1) {
    accL  += __shfl_xor(accL, k);
    accEp += __shfl_xor(accEp, k);
    accEv += __shfl_xor(accEv, k);
  }
  if (ln == 0) { red[wid][0] = accL; red[wid][1] = accEp; red[wid][2] = accEv; }
  __syncthreads();
  if (tid < 3) {
    float s = 0.f;
    for (int i = 0; i < 8; ++i) s += red[i][tid];
    atomicAdd(&wsf[tid], s);
  }
}

__global__ void fin_kernel(const float* __restrict__ wacc, float* __restrict__ out) {
  if (threadIdx.x == 0 && blockIdx.x == 0) {
    out[0] = wacc[0] / 1104.f;
    out[1] = wacc[1] / 828.f;
    out[2] = wacc[2] / 828.f;
  }
}

extern "C" void kernel_launch(void* const* d_in, const int* in_sizes, int n_in,
                              void* d_out, int out_size, void* d_ws, size_t ws_size,
                              hipStream_t stream) {
  const float* states = (const float*)d_in[0];
  const float* Wih0 = (const float*)d_in[1];
  const float* Whh0 = (const float*)d_in[2];
  const float* bih0 = (const float*)d_in[3];
  const float* bhh0 = (const float*)d_in[4];
  const float* Wih1 = (const float*)d_in[5];
  const float* Whh1 = (const float*)d_in[6];
  const float* bih1 = (const float*)d_in[7];
  const float* bhh1 = (const float*)d_in[8];
  const float* W1   = (const float*)d_in[9];
  const float* b1   = (const float*)d_in[10];
  const float* W2   = (const float*)d_in[11];
  const float* b2   = (const float*)d_in[12];
  const float* Wm   = (const float*)d_in[13];
  const float* bm   = (const float*)d_in[14];

  float* wsf = (float*)d_ws;
  u8* wb = (u8*)d_ws + WB_BYTE_OFF;

  int prep_blocks = (NA3 + 255) / 256;
  if (prep_blocks > 2048) prep_blocks = 2048;
  prep_kernel<<<prep_blocks, 256, 0, stream>>>(states, Wih0, Whh0, bih0, bhh0,
                                               Wih1, Whh1, bih1, bhh1,
                                               W1, W2, wb, wsf);
  rnn_kernel<<<184, 512, 0, stream>>>(states, wb, wsf, b1, b2, Wm, bm);
  fin_kernel<<<1, 64, 0, stream>>>(wsf, (float*)d_out);
}